// Round 2
// baseline (2796.282 us; speedup 1.0000x reference)
//
#include <hip/hip_runtime.h>

#define SQ 1024
#define DIM 1024
#define NH 16
#define HDIM 64
#define FFD 4096
#define NV 51200
#define NL 8

typedef __bf16 bf16x8 __attribute__((ext_vector_type(8)));
typedef float f32x4 __attribute__((ext_vector_type(4)));

__device__ __forceinline__ float bf2f(unsigned short u) {
    union { unsigned int i; float f; } v; v.i = ((unsigned int)u) << 16; return v.f;
}
__device__ __forceinline__ unsigned short f2bf(float f) {
    union { float f; unsigned int i; } v; v.f = f;
    unsigned int r = v.i + 0x7fffu + ((v.i >> 16) & 1u);
    return (unsigned short)(r >> 16);
}
__device__ __forceinline__ float rdf(const void* p, long i, int isbf) {
    return isbf ? bf2f(((const unsigned short*)p)[i]) : ((const float*)p)[i];
}
__device__ __forceinline__ float gelu_tanh(float x) {
    float x3 = x * x * x;
    return 0.5f * x * (1.0f + tanhf(0.79788456080286535588f * (x + 0.044715f * x3)));
}

#define GLD16(gp, lp) __builtin_amdgcn_global_load_lds( \
    (__attribute__((address_space(1))) void*)(gp), \
    (__attribute__((address_space(3))) void*)(lp), 16, 0, 0)

// dtype probe: ln1_w is all-ones. bf16 pair => 0x3F803F80, fp32 => 0x3F800000
__global__ void probe_kernel(const unsigned int* __restrict__ w, int* __restrict__ flag) {
    if (threadIdx.x == 0) *flag = (w[0] == 0x3F803F80u) ? 1 : 0;
}

__global__ void sincos_kernel(const int* __restrict__ pos, float2* __restrict__ sc) {
    const int t = blockIdx.x * 256 + threadIdx.x;
    if (t >= SQ * 16) return;
    const int s = t >> 4, i = t & 15;
    const float ang = (float)pos[s] * powf(10000.0f, -(float)i / 16.0f);
    sc[t] = make_float2(sinf(ang), cosf(ang));
}

__global__ void embed_kernel(const int* __restrict__ idx, const void* __restrict__ emb,
                             float* __restrict__ x, const int* __restrict__ flagp) {
    const int s = blockIdx.x;
    const int d = threadIdx.x * 4;
    const int row = idx[s];
    float4 f;
    if (*flagp) {
        ushort4 e = *reinterpret_cast<const ushort4*>((const unsigned short*)emb + (long)row * DIM + d);
        f = make_float4(bf2f(e.x), bf2f(e.y), bf2f(e.z), bf2f(e.w));
    } else {
        f = *reinterpret_cast<const float4*>((const float*)emb + (long)row * DIM + d);
    }
    *reinterpret_cast<float4*>(x + (long)s * DIM + d) = f;
}

// layernorm; w/b indexed at element offset woff (layer slice) in flag dtype
__global__ __launch_bounds__(256) void ln_kernel(const float* __restrict__ x,
                                                 const void* __restrict__ w,
                                                 const void* __restrict__ b,
                                                 long woff,
                                                 unsigned short* __restrict__ out,
                                                 const int* __restrict__ flagp) {
    __shared__ float red[8];
    const int isbf = *flagp;
    const int s = blockIdx.x, tid = threadIdx.x;
    const float* xr = x + (long)s * DIM;
    float4 v = reinterpret_cast<const float4*>(xr)[tid];
    float sum = v.x + v.y + v.z + v.w;
    float sq = v.x * v.x + v.y * v.y + v.z * v.z + v.w * v.w;
    #pragma unroll
    for (int off = 32; off; off >>= 1) { sum += __shfl_xor(sum, off); sq += __shfl_xor(sq, off); }
    const int wid = tid >> 6, lane = tid & 63;
    if (lane == 0) { red[wid * 2] = sum; red[wid * 2 + 1] = sq; }
    __syncthreads();
    sum = red[0] + red[2] + red[4] + red[6];
    sq  = red[1] + red[3] + red[5] + red[7];
    const float mu = sum * (1.0f / DIM);
    const float var = sq * (1.0f / DIM) - mu * mu;
    const float rstd = rsqrtf(var + 1e-5f);
    const int d = tid * 4;
    float vv[4] = {v.x, v.y, v.z, v.w};
    ushort4 o;
    unsigned short* op = (unsigned short*)&o;
    #pragma unroll
    for (int j = 0; j < 4; j++)
        op[j] = f2bf((vv[j] - mu) * rstd * rdf(w, woff + d + j, isbf) + rdf(b, woff + d + j, isbf));
    *reinterpret_cast<ushort4*>(out + (long)s * DIM + d) = o;
}

// C(MxN) = A(MxK) @ B(NxK)^T; A internal bf16; B/bias flag dtype at element offsets boff/bioff
template <int EPI, bool DYNOUT>
__global__ __launch_bounds__(256) void gemm_bt(const unsigned short* __restrict__ A,
                                               const void* __restrict__ B, long boff,
                                               const void* __restrict__ bias, long bioff,
                                               void* __restrict__ C,
                                               int M, int N, int K,
                                               const int* __restrict__ flagp) {
    __shared__ unsigned short As[128 * 64];
    __shared__ unsigned short Bs[128 * 64];
    const int isbf = *flagp;
    const int tid = threadIdx.x;
    const int m0 = blockIdx.y * 128, n0 = blockIdx.x * 128;
    const int lane = tid & 63, wid = tid >> 6;
    const int l15 = lane & 15, lhi = lane >> 4;
    const int wr = wid >> 1, wc = wid & 1;

    f32x4 acc[4][4];
    #pragma unroll
    for (int i = 0; i < 4; i++)
        #pragma unroll
        for (int j = 0; j < 4; j++) acc[i][j] = (f32x4){0.f, 0.f, 0.f, 0.f};

    const int nk = K >> 6;
    const int wbase = (tid & ~63) * 8;
    for (int kt = 0; kt < nk; kt++) {
        __syncthreads();
        #pragma unroll
        for (int i = 0; i < 4; i++) {
            const int e = (i * 256 + tid) * 8;
            GLD16(A + (long)(m0 + (e >> 6)) * K + kt * 64 + (e & 63), &As[i * 2048 + wbase]);
        }
        if (isbf) {
            const unsigned short* Bh = (const unsigned short*)B + boff;
            #pragma unroll
            for (int i = 0; i < 4; i++) {
                const int e = (i * 256 + tid) * 8;
                GLD16(Bh + (long)(n0 + (e >> 6)) * K + kt * 64 + (e & 63), &Bs[i * 2048 + wbase]);
            }
        } else {
            const float* Bf = (const float*)B + boff;
            #pragma unroll
            for (int i = 0; i < 8; i++) {
                const int e = (i * 256 + tid) * 4;
                const int r = e >> 6, c = e & 63;
                float4 v = *reinterpret_cast<const float4*>(Bf + (long)(n0 + r) * K + kt * 64 + c);
                ushort4 o = make_ushort4(f2bf(v.x), f2bf(v.y), f2bf(v.z), f2bf(v.w));
                *reinterpret_cast<ushort4*>(&Bs[e]) = o;
            }
        }
        asm volatile("s_waitcnt vmcnt(0)" ::: "memory");
        __syncthreads();
        #pragma unroll
        for (int ks = 0; ks < 2; ks++) {
            bf16x8 af[4], bfr[4];
            #pragma unroll
            for (int mf = 0; mf < 4; mf++)
                af[mf] = *reinterpret_cast<const bf16x8*>(&As[(wr * 64 + mf * 16 + l15) * 64 + ks * 32 + lhi * 8]);
            #pragma unroll
            for (int nf = 0; nf < 4; nf++)
                bfr[nf] = *reinterpret_cast<const bf16x8*>(&Bs[(wc * 64 + nf * 16 + l15) * 64 + ks * 32 + lhi * 8]);
            #pragma unroll
            for (int mf = 0; mf < 4; mf++)
                #pragma unroll
                for (int nf = 0; nf < 4; nf++)
                    acc[mf][nf] = __builtin_amdgcn_mfma_f32_16x16x32_bf16(af[mf], bfr[nf], acc[mf][nf], 0, 0, 0);
        }
    }
    #pragma unroll
    for (int nf = 0; nf < 4; nf++) {
        const int col = n0 + wc * 64 + nf * 16 + l15;
        float bv = 0.f;
        if constexpr (EPI >= 1) bv = rdf(bias, bioff + col, isbf);
        #pragma unroll
        for (int mf = 0; mf < 4; mf++) {
            #pragma unroll
            for (int j = 0; j < 4; j++) {
                float v = acc[mf][nf][j] + bv;
                if constexpr (EPI == 2) v = gelu_tanh(v);
                const int row = m0 + wr * 64 + mf * 16 + lhi * 4 + j;
                if (DYNOUT && !isbf) ((float*)C)[(long)row * N + col] = v;
                else ((unsigned short*)C)[(long)row * N + col] = f2bf(v);
            }
        }
    }
}

__global__ void rope_kernel(const unsigned short* __restrict__ qkv, const float2* __restrict__ sc,
                            unsigned short* __restrict__ qt, unsigned short* __restrict__ kt,
                            unsigned short* __restrict__ vt) {
    const int t = blockIdx.x * 256 + threadIdx.x;
    const int i = t & 31;
    const int h = (t >> 5) & 15;
    const int s = t >> 9;
    const int g = h >> 2, hh = h & 3;
    const long base = (long)s * (3 * DIM) + g * 768 + hh * 64;
    const int d0 = i * 2;
    float q0 = bf2f(qkv[base + d0]),       q1 = bf2f(qkv[base + d0 + 1]);
    float v0 = bf2f(qkv[base + 256 + d0]), v1 = bf2f(qkv[base + 256 + d0 + 1]);
    float k0 = bf2f(qkv[base + 512 + d0]), k1 = bf2f(qkv[base + 512 + d0 + 1]);
    if (d0 < 32) {
        float2 scv = sc[s * 16 + i];
        const float sn = scv.x, cs = scv.y;
        float tq0 = q0 * cs - q1 * sn, tq1 = q1 * cs + q0 * sn;
        float tk0 = k0 * cs - k1 * sn, tk1 = k1 * cs + k0 * sn;
        q0 = tq0; q1 = tq1; k0 = tk0; k1 = tk1;
    }
    const long ob = ((long)h * SQ + s) * HDIM + d0;
    qt[ob] = f2bf(q0); qt[ob + 1] = f2bf(q1);
    kt[ob] = f2bf(k0); kt[ob + 1] = f2bf(k1);
    vt[(long)h * (HDIM * SQ) + (long)d0 * SQ + s] = f2bf(v0);
    vt[(long)h * (HDIM * SQ) + (long)(d0 + 1) * SQ + s] = f2bf(v1);
}

__global__ __launch_bounds__(256) void attn_kernel(const unsigned short* __restrict__ qt,
                                                   const unsigned short* __restrict__ kt,
                                                   const unsigned short* __restrict__ vt,
                                                   unsigned short* __restrict__ y) {
    __shared__ unsigned short Ks[32 * 64];
    __shared__ unsigned short Vs[64 * 32];
    __shared__ unsigned short Ps[4][16 * 32];
    const int h = blockIdx.y, qb = blockIdx.x;
    const int tid = threadIdx.x, lane = tid & 63, wid = tid >> 6;
    const int l15 = lane & 15, lhi = lane >> 4;
    const int q0 = qb * 64 + wid * 16;

    bf16x8 aq[2];
    {
        const unsigned short* qp = qt + ((long)(h * SQ + q0 + l15)) * HDIM;
        aq[0] = *reinterpret_cast<const bf16x8*>(qp + lhi * 8);
        aq[1] = *reinterpret_cast<const bf16x8*>(qp + 32 + lhi * 8);
    }
    f32x4 o[4];
    #pragma unroll
    for (int nf = 0; nf < 4; nf++) o[nf] = (f32x4){0.f, 0.f, 0.f, 0.f};
    float mrow[4] = {-1e30f, -1e30f, -1e30f, -1e30f};
    float lrow[4] = {0.f, 0.f, 0.f, 0.f};

    const int nkv = (qb + 1) * 2;
    const int wb8 = (tid & ~63) * 8;
    for (int kv = 0; kv < nkv; kv++) {
        const int kv0 = kv * 32;
        __syncthreads();
        {
            const int e = tid * 8;
            GLD16(kt + ((long)(h * SQ + kv0 + (e >> 6))) * HDIM + (e & 63), &Ks[wb8]);
            GLD16(vt + (long)h * (HDIM * SQ) + (long)(e >> 5) * SQ + kv0 + (e & 31), &Vs[wb8]);
        }
        asm volatile("s_waitcnt vmcnt(0)" ::: "memory");
        __syncthreads();

        f32x4 sa[2];
        sa[0] = (f32x4){0.f, 0.f, 0.f, 0.f};
        sa[1] = (f32x4){0.f, 0.f, 0.f, 0.f};
        #pragma unroll
        for (int hc = 0; hc < 2; hc++)
            #pragma unroll
            for (int ks = 0; ks < 2; ks++) {
                bf16x8 bk = *reinterpret_cast<const bf16x8*>(&Ks[(hc * 16 + l15) * 64 + ks * 32 + lhi * 8]);
                sa[hc] = __builtin_amdgcn_mfma_f32_16x16x32_bf16(aq[ks], bk, sa[hc], 0, 0, 0);
            }
        float pr[2][4], mb[4];
        #pragma unroll
        for (int j = 0; j < 4; j++) {
            const int qi = q0 + lhi * 4 + j;
            #pragma unroll
            for (int hc = 0; hc < 2; hc++) {
                const int ki = kv0 + hc * 16 + l15;
                const float sv = sa[hc][j] * 0.125f;
                pr[hc][j] = (ki <= qi) ? sv : -1e30f;
            }
            mb[j] = fmaxf(pr[0][j], pr[1][j]);
        }
        #pragma unroll
        for (int off = 1; off < 16; off <<= 1)
            #pragma unroll
            for (int j = 0; j < 4; j++) mb[j] = fmaxf(mb[j], __shfl_xor(mb[j], off));
        float alpha[4], psum[4];
        #pragma unroll
        for (int j = 0; j < 4; j++) {
            const float mn = fmaxf(mrow[j], mb[j]);
            alpha[j] = __expf(mrow[j] - mn);
            mrow[j] = mn;
            pr[0][j] = __expf(pr[0][j] - mn);
            pr[1][j] = __expf(pr[1][j] - mn);
            psum[j] = pr[0][j] + pr[1][j];
        }
        #pragma unroll
        for (int off = 1; off < 16; off <<= 1)
            #pragma unroll
            for (int j = 0; j < 4; j++) psum[j] += __shfl_xor(psum[j], off);
        #pragma unroll
        for (int j = 0; j < 4; j++) lrow[j] = lrow[j] * alpha[j] + psum[j];
        #pragma unroll
        for (int nf = 0; nf < 4; nf++)
            #pragma unroll
            for (int j = 0; j < 4; j++) o[nf][j] *= alpha[j];
        #pragma unroll
        for (int hc = 0; hc < 2; hc++)
            #pragma unroll
            for (int j = 0; j < 4; j++)
                Ps[wid][(lhi * 4 + j) * 32 + hc * 16 + l15] = f2bf(pr[hc][j]);
        bf16x8 ap = *reinterpret_cast<const bf16x8*>(&Ps[wid][l15 * 32 + lhi * 8]);
        #pragma unroll
        for (int nf = 0; nf < 4; nf++) {
            bf16x8 bv = *reinterpret_cast<const bf16x8*>(&Vs[(nf * 16 + l15) * 32 + lhi * 8]);
            o[nf] = __builtin_amdgcn_mfma_f32_16x16x32_bf16(ap, bv, o[nf], 0, 0, 0);
        }
    }
    #pragma unroll
    for (int nf = 0; nf < 4; nf++)
        #pragma unroll
        for (int j = 0; j < 4; j++) {
            const int row = q0 + lhi * 4 + j;
            y[(long)row * DIM + h * HDIM + nf * 16 + l15] = f2bf(o[nf][j] / lrow[j]);
        }
}

__global__ void add_kernel(float* __restrict__ x, const unsigned short* __restrict__ a,
                           const unsigned short* __restrict__ m) {
    const int t = blockIdx.x * 256 + threadIdx.x;
    const long i = (long)t * 4;
    ushort4 av = *reinterpret_cast<const ushort4*>(a + i);
    ushort4 mv = *reinterpret_cast<const ushort4*>(m + i);
    float4 xv = *reinterpret_cast<const float4*>(x + i);
    xv.x += bf2f(av.x) + bf2f(mv.x);
    xv.y += bf2f(av.y) + bf2f(mv.y);
    xv.z += bf2f(av.z) + bf2f(mv.z);
    xv.w += bf2f(av.w) + bf2f(mv.w);
    *reinterpret_cast<float4*>(x + i) = xv;
}

extern "C" void kernel_launch(void* const* d_in, const int* in_sizes, int n_in,
                              void* d_out, int out_size, void* d_ws, size_t ws_size,
                              hipStream_t stream) {
    const int* idx   = (const int*)d_in[0];
    const int* pos   = (const int*)d_in[1];
    const void* emb  = d_in[2];
    const void* Wqkv = d_in[3];
    const void* Wo   = d_in[4];
    const void* ln1w = d_in[5];
    const void* ln1b = d_in[6];
    const void* fciw = d_in[7];
    const void* fcib = d_in[8];
    const void* fcow = d_in[9];
    const void* fcob = d_in[10];
    const void* lnfw = d_in[11];
    const void* lnfb = d_in[12];
    const void* lmw  = d_in[13];
    const void* lmb  = d_in[14];

    char* ws = (char*)d_ws;
    float* x           = (float*)ws;          ws += (long)SQ * DIM * 4;
    unsigned short* h  = (unsigned short*)ws; ws += (long)SQ * DIM * 2;
    unsigned short* qkv= (unsigned short*)ws; ws += (long)SQ * 3 * DIM * 2;
    unsigned short* qt = (unsigned short*)ws; ws += (long)NH * SQ * HDIM * 2;
    unsigned short* kt = (unsigned short*)ws; ws += (long)NH * SQ * HDIM * 2;
    unsigned short* vt = (unsigned short*)ws; ws += (long)NH * SQ * HDIM * 2;
    unsigned short* yb = (unsigned short*)ws; ws += (long)SQ * DIM * 2;
    unsigned short* ao = (unsigned short*)ws; ws += (long)SQ * DIM * 2;
    unsigned short* ff = (unsigned short*)ws; ws += (long)SQ * FFD * 2;
    unsigned short* mo = (unsigned short*)ws; ws += (long)SQ * DIM * 2;
    float2* sc         = (float2*)ws;         ws += (long)SQ * 16 * 8;
    int* flag          = (int*)ws;            ws += 256;

    probe_kernel<<<1, 64, 0, stream>>>((const unsigned int*)ln1w, flag);
    sincos_kernel<<<64, 256, 0, stream>>>(pos, sc);
    embed_kernel<<<SQ, 256, 0, stream>>>(idx, emb, x, flag);

    for (int l = 0; l < NL; l++) {
        ln_kernel<<<SQ, 256, 0, stream>>>(x, ln1w, ln1b, (long)l * DIM, h, flag);
        gemm_bt<0, false><<<dim3(24, 8), 256, 0, stream>>>(h, Wqkv, (long)l * 3 * DIM * DIM,
                                                           nullptr, 0, qkv, SQ, 3 * DIM, DIM, flag);
        rope_kernel<<<2048, 256, 0, stream>>>(qkv, sc, qt, kt, vt);
        attn_kernel<<<dim3(16, 16), 256, 0, stream>>>(qt, kt, vt, yb);
        gemm_bt<0, false><<<dim3(8, 8), 256, 0, stream>>>(yb, Wo, (long)l * DIM * DIM,
                                                          nullptr, 0, ao, SQ, DIM, DIM, flag);
        gemm_bt<2, false><<<dim3(32, 8), 256, 0, stream>>>(h, fciw, (long)l * FFD * DIM,
                                                           fcib, (long)l * FFD, ff, SQ, FFD, DIM, flag);
        gemm_bt<1, false><<<dim3(8, 8), 256, 0, stream>>>(ff, fcow, (long)l * DIM * FFD,
                                                          fcob, (long)l * DIM, mo, SQ, DIM, FFD, flag);
        add_kernel<<<SQ, 256, 0, stream>>>(x, ao, mo);
    }
    ln_kernel<<<SQ, 256, 0, stream>>>(x, lnfw, lnfb, 0, h, flag);
    gemm_bt<1, true><<<dim3(NV / 128, 8), 256, 0, stream>>>(h, lmw, 0, lmb, 0, d_out,
                                                            SQ, NV, DIM, flag);
}

// Round 3
// 1579.118 us; speedup vs baseline: 1.7708x; 1.7708x over previous
//
#include <hip/hip_runtime.h>

#define SQ 1024
#define DIM 1024
#define NH 16
#define HDIM 64
#define FFD 4096
#define NV 51200
#define NL 8
#define LDBUF 5120  // [yb(1024) | ff(4096)] row stride

typedef __bf16 bf16x8 __attribute__((ext_vector_type(8)));
typedef float f32x4 __attribute__((ext_vector_type(4)));

__device__ __forceinline__ unsigned short f2bf(float f) {
    union { float f; unsigned int i; } v; v.f = f;
    unsigned int r = v.i + 0x7fffu + ((v.i >> 16) & 1u);
    return (unsigned short)(r >> 16);
}
__device__ __forceinline__ float gelu_tanh(float x) {
    float x3 = x * x * x;
    return 0.5f * x * (1.0f + tanhf(0.79788456080286535588f * (x + 0.044715f * x3)));
}

#define GLD16(gp, lp) __builtin_amdgcn_global_load_lds( \
    (__attribute__((address_space(1))) void*)(gp), \
    (__attribute__((address_space(3))) void*)(lp), 16, 0, 0)

// ---------------- sin/cos table ----------------
__global__ void sincos_kernel(const int* __restrict__ pos, float2* __restrict__ sc) {
    const int t = blockIdx.x * 256 + threadIdx.x;
    if (t >= SQ * 16) return;
    const int s = t >> 4, i = t & 15;
    const float ang = (float)pos[s] * powf(10000.0f, -(float)i / 16.0f);
    sc[t] = make_float2(sinf(ang), cosf(ang));
}

// ---------------- embedding gather (fp32 -> fp32 residual) ----------------
__global__ void embed_kernel(const int* __restrict__ idx, const float* __restrict__ emb,
                             float* __restrict__ x) {
    const int s = blockIdx.x;
    const int d = threadIdx.x * 4;
    const int row = idx[s];
    *reinterpret_cast<float4*>(x + (long)s * DIM + d) =
        *reinterpret_cast<const float4*>(emb + (long)row * DIM + d);
}

// ---------------- fused (residual reduce) + layernorm ----------------
// RED: x += part[0..3] (split-K partials of Wo/fc_out merged GEMM, bias already in slice 0)
template <bool RED>
__global__ __launch_bounds__(256) void ln_kernel(float* __restrict__ x,
                                                 const float* __restrict__ part,
                                                 const float* __restrict__ w,
                                                 const float* __restrict__ b,
                                                 unsigned short* __restrict__ out) {
    __shared__ float red[8];
    const int s = blockIdx.x, tid = threadIdx.x;
    const long fidx = (long)s * 256 + tid;  // float4 index
    float4 v = reinterpret_cast<const float4*>(x)[fidx];
    if (RED) {
        #pragma unroll
        for (int z = 0; z < 4; z++) {
            float4 p = reinterpret_cast<const float4*>(part + (long)z * SQ * DIM)[fidx];
            v.x += p.x; v.y += p.y; v.z += p.z; v.w += p.w;
        }
        reinterpret_cast<float4*>(x)[fidx] = v;
    }
    float sum = v.x + v.y + v.z + v.w;
    float sq = v.x * v.x + v.y * v.y + v.z * v.z + v.w * v.w;
    #pragma unroll
    for (int off = 32; off; off >>= 1) { sum += __shfl_xor(sum, off); sq += __shfl_xor(sq, off); }
    const int wid = tid >> 6, lane = tid & 63;
    if (lane == 0) { red[wid * 2] = sum; red[wid * 2 + 1] = sq; }
    __syncthreads();
    sum = red[0] + red[2] + red[4] + red[6];
    sq  = red[1] + red[3] + red[5] + red[7];
    const float mu = sum * (1.0f / DIM);
    const float var = sq * (1.0f / DIM) - mu * mu;
    const float rstd = rsqrtf(var + 1e-5f);
    const int d = tid * 4;
    float vv[4] = {v.x, v.y, v.z, v.w};
    ushort4 o;
    unsigned short* op = (unsigned short*)&o;
    #pragma unroll
    for (int j = 0; j < 4; j++)
        op[j] = f2bf((vv[j] - mu) * rstd * w[d + j] + b[d + j]);
    *reinterpret_cast<ushort4*>(out + (long)s * DIM + d) = o;
}

// ---------------- GEMM: C(1024 x N) = A(1024 x K, bf16) @ B(N x K, fp32)^T ----------------
// 128x128 tiles, BK=64, flat grid with XCD-chunked row-fast swizzle.
// MERGED: K = 5120 split over B1 (k<1024, Wo) and B2 (k>=1024, fc_out); split-K=4 over grid,
//         each kz writes its own fp32 partial (bias added by kz==0 only).
// EPI: 0 none, 1 +bias, 2 gelu(x+bias).  F32OUT: C is fp32 (else bf16).
template <int EPI, bool MERGED, bool F32OUT>
__global__ __launch_bounds__(256) void gemm_k(const unsigned short* __restrict__ A, int lda,
                                              const float* __restrict__ B1, int ldb1,
                                              const float* __restrict__ B2, int ldb2,
                                              const float* __restrict__ bias,
                                              void* __restrict__ C, int ldc, int K) {
    __shared__ unsigned short As[128 * 64];
    __shared__ unsigned short Bs[128 * 64];
    const int tid = threadIdx.x;
    const int nwg = gridDim.x, qch = nwg >> 3;
    const int sb = (blockIdx.x & 7) * qch + (blockIdx.x >> 3);  // XCD-chunked (nwg%8==0)
    int mb, nb, kz, kt0, ktn;
    if (MERGED) { kz = sb & 3; nb = (sb >> 2) & 7; mb = sb >> 5; kt0 = kz * 20; ktn = kt0 + 20; }
    else        { kz = 0; mb = sb & 7; nb = sb >> 3; kt0 = 0; ktn = K >> 6; }
    const int m0 = mb * 128, n0 = nb * 128;
    const int lane = tid & 63, wid = tid >> 6;
    const int l15 = lane & 15, lhi = lane >> 4;
    const int wr = wid >> 1, wc = wid & 1;

    f32x4 acc[4][4];
    #pragma unroll
    for (int i = 0; i < 4; i++)
        #pragma unroll
        for (int j = 0; j < 4; j++) acc[i][j] = (f32x4){0.f, 0.f, 0.f, 0.f};

    const int wbase = (tid & ~63) * 8;  // wave-uniform LDS element base for GLD16
    for (int kt = kt0; kt < ktn; kt++) {
        const int k0 = kt << 6;
        const float* Bp; int ldb, kk;
        if (MERGED && k0 >= 1024) { Bp = B2; ldb = ldb2; kk = k0 - 1024; }
        else                      { Bp = B1; ldb = ldb1; kk = k0; }
        __syncthreads();
        #pragma unroll
        for (int i = 0; i < 4; i++) {
            const int e = (i * 256 + tid) * 8;
            GLD16(A + (long)(m0 + (e >> 6)) * lda + k0 + (e & 63), &As[i * 2048 + wbase]);
        }
        #pragma unroll
        for (int i = 0; i < 4; i++) {
            const int e = (i * 256 + tid) * 8;
            const float* src = Bp + (long)(n0 + (e >> 6)) * ldb + kk + (e & 63);
            float4 v0 = *reinterpret_cast<const float4*>(src);
            float4 v1 = *reinterpret_cast<const float4*>(src + 4);
            bf16x8 w;
            w[0] = (__bf16)v0.x; w[1] = (__bf16)v0.y; w[2] = (__bf16)v0.z; w[3] = (__bf16)v0.w;
            w[4] = (__bf16)v1.x; w[5] = (__bf16)v1.y; w[6] = (__bf16)v1.z; w[7] = (__bf16)v1.w;
            *reinterpret_cast<bf16x8*>(&Bs[e]) = w;
        }
        asm volatile("s_waitcnt vmcnt(0)" ::: "memory");
        __syncthreads();
        #pragma unroll
        for (int ks = 0; ks < 2; ks++) {
            bf16x8 af[4], bfr[4];
            #pragma unroll
            for (int mf = 0; mf < 4; mf++)
                af[mf] = *reinterpret_cast<const bf16x8*>(&As[(wr * 64 + mf * 16 + l15) * 64 + ks * 32 + lhi * 8]);
            #pragma unroll
            for (int nf = 0; nf < 4; nf++)
                bfr[nf] = *reinterpret_cast<const bf16x8*>(&Bs[(wc * 64 + nf * 16 + l15) * 64 + ks * 32 + lhi * 8]);
            #pragma unroll
            for (int mf = 0; mf < 4; mf++)
                #pragma unroll
                for (int nf = 0; nf < 4; nf++)
                    acc[mf][nf] = __builtin_amdgcn_mfma_f32_16x16x32_bf16(af[mf], bfr[nf], acc[mf][nf], 0, 0, 0);
        }
    }
    float* Cf = (float*)C + (MERGED ? (long)kz * SQ * DIM : 0);
    #pragma unroll
    for (int nf = 0; nf < 4; nf++) {
        const int col = n0 + wc * 64 + nf * 16 + l15;
        float bv = 0.f;
        if constexpr (EPI >= 1) { if (!MERGED || kz == 0) bv = bias[col]; }
        #pragma unroll
        for (int mf = 0; mf < 4; mf++) {
            #pragma unroll
            for (int j = 0; j < 4; j++) {
                float v = acc[mf][nf][j] + bv;
                if constexpr (EPI == 2) v = gelu_tanh(v);
                const int row = m0 + wr * 64 + mf * 16 + lhi * 4 + j;
                if (F32OUT) Cf[(long)row * ldc + col] = v;
                else ((unsigned short*)C)[(long)row * ldc + col] = f2bf(v);
            }
        }
    }
}

// ---------------- RoPE + QKV scatter (internal bf16) ----------------
__global__ void rope_kernel(const unsigned short* __restrict__ qkv, const float2* __restrict__ sc,
                            unsigned short* __restrict__ qt, unsigned short* __restrict__ kt,
                            unsigned short* __restrict__ vt) {
    const int t = blockIdx.x * 256 + threadIdx.x;
    const int i = t & 31;
    const int h = (t >> 5) & 15;
    const int s = t >> 9;
    const int g = h >> 2, hh = h & 3;
    const long base = (long)s * (3 * DIM) + g * 768 + hh * 64;
    const int d0 = i * 2;
    float q0, q1, v0, v1, k0, k1;
    {
        union { unsigned int u; struct { unsigned short lo, hi; }; } a, b, c;
        a.u = *(const unsigned int*)(qkv + base + d0);
        b.u = *(const unsigned int*)(qkv + base + 256 + d0);
        c.u = *(const unsigned int*)(qkv + base + 512 + d0);
        union { unsigned int i; float f; } t0;
        t0.i = (unsigned int)a.lo << 16; q0 = t0.f; t0.i = (unsigned int)a.hi << 16; q1 = t0.f;
        t0.i = (unsigned int)b.lo << 16; v0 = t0.f; t0.i = (unsigned int)b.hi << 16; v1 = t0.f;
        t0.i = (unsigned int)c.lo << 16; k0 = t0.f; t0.i = (unsigned int)c.hi << 16; k1 = t0.f;
    }
    if (d0 < 32) {
        float2 scv = sc[s * 16 + i];
        const float sn = scv.x, cs = scv.y;
        float tq0 = q0 * cs - q1 * sn, tq1 = q1 * cs + q0 * sn;
        float tk0 = k0 * cs - k1 * sn, tk1 = k1 * cs + k0 * sn;
        q0 = tq0; q1 = tq1; k0 = tk0; k1 = tk1;
    }
    const long ob = ((long)h * SQ + s) * HDIM + d0;
    qt[ob] = f2bf(q0); qt[ob + 1] = f2bf(q1);
    kt[ob] = f2bf(k0); kt[ob + 1] = f2bf(k1);
    vt[(long)h * (HDIM * SQ) + (long)d0 * SQ + s] = f2bf(v0);
    vt[(long)h * (HDIM * SQ) + (long)(d0 + 1) * SQ + s] = f2bf(v1);
}

// ---------------- causal flash attention, KVBLK=64 ----------------
// grid (16, NH); wave w owns q rows qb*64 + w*16 .. +16; writes into buf (ldc=LDBUF)
__global__ __launch_bounds__(256) void attn_kernel(const unsigned short* __restrict__ qt,
                                                   const unsigned short* __restrict__ kt,
                                                   const unsigned short* __restrict__ vt,
                                                   unsigned short* __restrict__ y) {
    __shared__ unsigned short Ks[64 * 64];    // [kv][d]
    __shared__ unsigned short Vs[64 * 64];    // [d][kv]
    __shared__ unsigned short Ps[4][16 * 64]; // per-wave P relayout
    const int h = blockIdx.y;
    const int qb = (int)gridDim.x - 1 - (int)blockIdx.x;  // big blocks dispatch first
    const int tid = threadIdx.x, lane = tid & 63, wid = tid >> 6;
    const int l15 = lane & 15, lhi = lane >> 4;
    const int q0 = qb * 64 + wid * 16;

    bf16x8 aq[2];
    {
        const unsigned short* qp = qt + ((long)(h * SQ + q0 + l15)) * HDIM;
        aq[0] = *reinterpret_cast<const bf16x8*>(qp + lhi * 8);
        aq[1] = *reinterpret_cast<const bf16x8*>(qp + 32 + lhi * 8);
    }
    f32x4 o[4];
    #pragma unroll
    for (int nf = 0; nf < 4; nf++) o[nf] = (f32x4){0.f, 0.f, 0.f, 0.f};
    float mrow[4] = {-1e30f, -1e30f, -1e30f, -1e30f};
    float lrow[4] = {0.f, 0.f, 0.f, 0.f};

    const int wb8 = (tid & ~63) * 8;
    for (int kvt = 0; kvt <= qb; kvt++) {
        const int kv0 = kvt * 64;
        __syncthreads();
        #pragma unroll
        for (int i = 0; i < 2; i++) {
            const int e = (i * 256 + tid) * 8;
            GLD16(kt + ((long)(h * SQ + kv0 + (e >> 6))) * HDIM + (e & 63), &Ks[i * 2048 + wb8]);
            GLD16(vt + (long)h * (HDIM * SQ) + (long)(e >> 6) * SQ + kv0 + (e & 63), &Vs[i * 2048 + wb8]);
        }
        asm volatile("s_waitcnt vmcnt(0)" ::: "memory");
        __syncthreads();

        f32x4 sa[4];
        #pragma unroll
        for (int hc = 0; hc < 4; hc++) sa[hc] = (f32x4){0.f, 0.f, 0.f, 0.f};
        #pragma unroll
        for (int hc = 0; hc < 4; hc++)
            #pragma unroll
            for (int ks = 0; ks < 2; ks++) {
                bf16x8 bk = *reinterpret_cast<const bf16x8*>(&Ks[(hc * 16 + l15) * 64 + ks * 32 + lhi * 8]);
                sa[hc] = __builtin_amdgcn_mfma_f32_16x16x32_bf16(aq[ks], bk, sa[hc], 0, 0, 0);
            }
        float pr[4][4], mb[4];
        #pragma unroll
        for (int j = 0; j < 4; j++) {
            const int qi = q0 + lhi * 4 + j;
            #pragma unroll
            for (int hc = 0; hc < 4; hc++) {
                const int ki = kv0 + hc * 16 + l15;
                const float sv = sa[hc][j] * 0.125f;
                pr[hc][j] = (ki <= qi) ? sv : -1e30f;
            }
            mb[j] = fmaxf(fmaxf(pr[0][j], pr[1][j]), fmaxf(pr[2][j], pr[3][j]));
        }
        #pragma unroll
        for (int off = 1; off < 16; off <<= 1)
            #pragma unroll
            for (int j = 0; j < 4; j++) mb[j] = fmaxf(mb[j], __shfl_xor(mb[j], off));
        float alpha[4], psum[4];
        #pragma unroll
        for (int j = 0; j < 4; j++) {
            const float mn = fmaxf(mrow[j], mb[j]);
            alpha[j] = __expf(mrow[j] - mn);
            mrow[j] = mn;
            psum[j] = 0.f;
            #pragma unroll
            for (int hc = 0; hc < 4; hc++) { pr[hc][j] = __expf(pr[hc][j] - mn); psum[j] += pr[hc][j]; }
        }
        #pragma unroll
        for (int off = 1; off < 16; off <<= 1)
            #pragma unroll
            for (int j = 0; j < 4; j++) psum[j] += __shfl_xor(psum[j], off);
        #pragma unroll
        for (int j = 0; j < 4; j++) lrow[j] = lrow[j] * alpha[j] + psum[j];
        #pragma unroll
        for (int nf = 0; nf < 4; nf++)
            #pragma unroll
            for (int j = 0; j < 4; j++) o[nf][j] *= alpha[j];
        #pragma unroll
        for (int hc = 0; hc < 4; hc++)
            #pragma unroll
            for (int j = 0; j < 4; j++)
                Ps[wid][(lhi * 4 + j) * 64 + hc * 16 + l15] = f2bf(pr[hc][j]);
        bf16x8 ap[2];
        ap[0] = *reinterpret_cast<const bf16x8*>(&Ps[wid][l15 * 64 + lhi * 8]);
        ap[1] = *reinterpret_cast<const bf16x8*>(&Ps[wid][l15 * 64 + 32 + lhi * 8]);
        #pragma unroll
        for (int nf = 0; nf < 4; nf++)
            #pragma unroll
            for (int ks2 = 0; ks2 < 2; ks2++) {
                bf16x8 bv = *reinterpret_cast<const bf16x8*>(&Vs[(nf * 16 + l15) * 64 + ks2 * 32 + lhi * 8]);
                o[nf] = __builtin_amdgcn_mfma_f32_16x16x32_bf16(ap[ks2], bv, o[nf], 0, 0, 0);
            }
    }
    #pragma unroll
    for (int nf = 0; nf < 4; nf++)
        #pragma unroll
        for (int j = 0; j < 4; j++) {
            const int row = q0 + lhi * 4 + j;
            y[(long)row * LDBUF + h * HDIM + nf * 16 + l15] = f2bf(o[nf][j] / lrow[j]);
        }
}

extern "C" void kernel_launch(void* const* d_in, const int* in_sizes, int n_in,
                              void* d_out, int out_size, void* d_ws, size_t ws_size,
                              hipStream_t stream) {
    const int* idx    = (const int*)d_in[0];
    const int* pos    = (const int*)d_in[1];
    const float* emb  = (const float*)d_in[2];
    const float* Wqkv = (const float*)d_in[3];
    const float* Wo   = (const float*)d_in[4];
    const float* ln1w = (const float*)d_in[5];
    const float* ln1b = (const float*)d_in[6];
    const float* fciw = (const float*)d_in[7];
    const float* fcib = (const float*)d_in[8];
    const float* fcow = (const float*)d_in[9];
    const float* fcob = (const float*)d_in[10];
    const float* lnfw = (const float*)d_in[11];
    const float* lnfb = (const float*)d_in[12];
    const float* lmw  = (const float*)d_in[13];
    const float* lmb  = (const float*)d_in[14];

    char* ws = (char*)d_ws;
    float* x           = (float*)ws;          ws += (long)SQ * DIM * 4;       // 4 MB fp32 residual
    float* parts       = (float*)ws;          ws += (long)4 * SQ * DIM * 4;   // 16 MB split-K partials
    unsigned short* h  = (unsigned short*)ws; ws += (long)SQ * DIM * 2;       // 2 MB ln out
    unsigned short* qkv= (unsigned short*)ws; ws += (long)SQ * 3 * DIM * 2;   // 6 MB
    unsigned short* qt = (unsigned short*)ws; ws += (long)NH * SQ * HDIM * 2; // 2 MB
    unsigned short* kt = (unsigned short*)ws; ws += (long)NH * SQ * HDIM * 2; // 2 MB
    unsigned short* vt = (unsigned short*)ws; ws += (long)NH * SQ * HDIM * 2; // 2 MB
    unsigned short* buf= (unsigned short*)ws; ws += (long)SQ * LDBUF * 2;     // 10 MB [yb|ff]
    float2* sc         = (float2*)ws;         ws += (long)SQ * 16 * 8;        // 128 KB

    sincos_kernel<<<64, 256, 0, stream>>>(pos, sc);
    embed_kernel<<<SQ, 256, 0, stream>>>(idx, emb, x);

    for (int l = 0; l < NL; l++) {
        if (l == 0) ln_kernel<false><<<SQ, 256, 0, stream>>>(x, nullptr, ln1w, ln1b, h);
        else ln_kernel<true><<<SQ, 256, 0, stream>>>(x, parts, ln1w + (long)l * DIM, ln1b + (long)l * DIM, h);
        // QKV: M=1024 N=3072 K=1024, grid 192
        gemm_k<0, false, false><<<192, 256, 0, stream>>>(h, DIM, Wqkv + (long)l * 3 * DIM * DIM, DIM,
                                                         nullptr, 0, nullptr, qkv, 3 * DIM, DIM);
        // fc_in + gelu: N=4096, writes ff half of buf, grid 256
        gemm_k<2, false, false><<<256, 256, 0, stream>>>(h, DIM, fciw + (long)l * FFD * DIM, DIM,
                                                         nullptr, 0, fcib + (long)l * FFD,
                                                         buf + DIM, LDBUF, DIM);
        rope_kernel<<<2048, 256, 0, stream>>>(qkv, sc, qt, kt, vt);
        attn_kernel<<<dim3(16, NH), 256, 0, stream>>>(qt, kt, vt, buf);
        // merged Wo+fc_out: [yb|ff](1024x5120) @ [Wo;fc_out]^T, split-K=4 -> partials
        gemm_k<1, true, true><<<256, 256, 0, stream>>>(buf, LDBUF, Wo + (long)l * DIM * DIM, DIM,
                                                       fcow + (long)l * DIM * FFD, FFD,
                                                       fcob + (long)l * DIM, parts, DIM, 5 * DIM);
    }
    ln_kernel<true><<<SQ, 256, 0, stream>>>(x, parts, lnfw, lnfb, h);
    // LM head: N=51200, grid 3200, fp32 out
    gemm_k<1, false, true><<<3200, 256, 0, stream>>>(h, DIM, lmw, DIM, nullptr, 0, lmb,
                                                     d_out, NV, DIM);
}

// Round 4
// 1498.041 us; speedup vs baseline: 1.8666x; 1.0541x over previous
//
#include <hip/hip_runtime.h>

#define SQ 1024
#define DIM 1024
#define NH 16
#define HDIM 64
#define FFD 4096
#define NV 51200
#define NL 8
#define LDBUF 5120  // [yb(1024) | ff(4096)] row stride

typedef __bf16 bf16x8 __attribute__((ext_vector_type(8)));
typedef float f32x4 __attribute__((ext_vector_type(4)));

__device__ __forceinline__ unsigned short f2bf(float f) {
    union { float f; unsigned int i; } v; v.f = f;
    unsigned int r = v.i + 0x7fffu + ((v.i >> 16) & 1u);
    return (unsigned short)(r >> 16);
}
__device__ __forceinline__ float gelu_tanh(float x) {
    float x3 = x * x * x;
    return 0.5f * x * (1.0f + tanhf(0.79788456080286535588f * (x + 0.044715f * x3)));
}

#define GLD16(gp, lp) __builtin_amdgcn_global_load_lds( \
    (__attribute__((address_space(1))) void*)(gp), \
    (__attribute__((address_space(3))) void*)(lp), 16, 0, 0)

// ---------------- fp32 -> bf16 weight conversion (RNE via native cast) ----------------
__global__ void cvt_kernel(const float* __restrict__ src, unsigned short* __restrict__ dst) {
    const long i = ((long)blockIdx.x * 256 + threadIdx.x) * 8;
    float4 a = *reinterpret_cast<const float4*>(src + i);
    float4 b = *reinterpret_cast<const float4*>(src + i + 4);
    bf16x8 w;
    w[0] = (__bf16)a.x; w[1] = (__bf16)a.y; w[2] = (__bf16)a.z; w[3] = (__bf16)a.w;
    w[4] = (__bf16)b.x; w[5] = (__bf16)b.y; w[6] = (__bf16)b.z; w[7] = (__bf16)b.w;
    *reinterpret_cast<bf16x8*>(dst + i) = w;
}

// ---------------- sin/cos table ----------------
__global__ void sincos_kernel(const int* __restrict__ pos, float2* __restrict__ sc) {
    const int t = blockIdx.x * 256 + threadIdx.x;
    if (t >= SQ * 16) return;
    const int s = t >> 4, i = t & 15;
    const float ang = (float)pos[s] * powf(10000.0f, -(float)i / 16.0f);
    sc[t] = make_float2(sinf(ang), cosf(ang));
}

// ---------------- embedding gather ----------------
__global__ void embed_kernel(const int* __restrict__ idx, const float* __restrict__ emb,
                             float* __restrict__ x) {
    const int s = blockIdx.x;
    const int d = threadIdx.x * 4;
    const int row = idx[s];
    *reinterpret_cast<float4*>(x + (long)s * DIM + d) =
        *reinterpret_cast<const float4*>(emb + (long)row * DIM + d);
}

// ---------------- fused (residual reduce) + layernorm ----------------
template <bool RED>
__global__ __launch_bounds__(256) void ln_kernel(float* __restrict__ x,
                                                 const float* __restrict__ part,
                                                 const float* __restrict__ w,
                                                 const float* __restrict__ b,
                                                 unsigned short* __restrict__ out) {
    __shared__ float red[8];
    const int s = blockIdx.x, tid = threadIdx.x;
    const long fidx = (long)s * 256 + tid;
    float4 v = reinterpret_cast<const float4*>(x)[fidx];
    if (RED) {
        #pragma unroll
        for (int z = 0; z < 4; z++) {
            float4 p = reinterpret_cast<const float4*>(part + (long)z * SQ * DIM)[fidx];
            v.x += p.x; v.y += p.y; v.z += p.z; v.w += p.w;
        }
        reinterpret_cast<float4*>(x)[fidx] = v;
    }
    float sum = v.x + v.y + v.z + v.w;
    float sq = v.x * v.x + v.y * v.y + v.z * v.z + v.w * v.w;
    #pragma unroll
    for (int off = 32; off; off >>= 1) { sum += __shfl_xor(sum, off); sq += __shfl_xor(sq, off); }
    const int wid = tid >> 6, lane = tid & 63;
    if (lane == 0) { red[wid * 2] = sum; red[wid * 2 + 1] = sq; }
    __syncthreads();
    sum = red[0] + red[2] + red[4] + red[6];
    sq  = red[1] + red[3] + red[5] + red[7];
    const float mu = sum * (1.0f / DIM);
    const float var = sq * (1.0f / DIM) - mu * mu;
    const float rstd = rsqrtf(var + 1e-5f);
    const int d = tid * 4;
    float vv[4] = {v.x, v.y, v.z, v.w};
    ushort4 o;
    unsigned short* op = (unsigned short*)&o;
    #pragma unroll
    for (int j = 0; j < 4; j++)
        op[j] = f2bf((vv[j] - mu) * rstd * w[d + j] + b[d + j]);
    *reinterpret_cast<ushort4*>(out + (long)s * DIM + d) = o;
}

// ---------------- GEMM, both operands bf16 via global_load_lds ----------------
// MODE 0: QKV+FCIN merged over N. A=h(lda DIM). nb<24: C1=qkv (ldc 3072), no bias.
//         nb>=24: B2=fc_in, C2=buf+DIM (ldc LDBUF), gelu(x+bias).   grid 448.
// MODE 1: Wo+FCOUT merged over K (5120), split-K=4 -> fp32 partials parts[kz],
//         bias on kz==0 only. A=buf(lda LDBUF).                      grid 256.
// MODE 2: LM head. C fp32 (ldc NV), +bias.                           grid 3200.
template <int MODE>
__global__ __launch_bounds__(256) void gemm_bb(const unsigned short* __restrict__ A, int lda,
                                               const unsigned short* __restrict__ B1,
                                               const unsigned short* __restrict__ B2,
                                               const float* __restrict__ bias,
                                               void* __restrict__ C1, void* __restrict__ C2) {
    __shared__ unsigned short As[128 * 64];
    __shared__ unsigned short Bs[128 * 64];
    const int tid = threadIdx.x;
    const int nwg = gridDim.x, qch = nwg >> 3;
    const int sb = (blockIdx.x & 7) * qch + (blockIdx.x >> 3);  // XCD-chunked (nwg%8==0)
    int mb, nb, kz, kt0, ktn;
    if (MODE == 1) { kz = sb & 3; nb = (sb >> 2) & 7; mb = sb >> 5; kt0 = kz * 20; ktn = kt0 + 20; }
    else           { kz = 0; mb = sb & 7; nb = sb >> 3; kt0 = 0; ktn = 16; }
    const int m0 = mb * 128, n0 = nb * 128;
    const int lane = tid & 63, wid = tid >> 6;
    const int l15 = lane & 15, lhi = lane >> 4;
    const int wr = wid >> 1, wc = wid & 1;

    // block-uniform B base for MODE 0/2
    const unsigned short* Bbase = B1;
    int nloc = n0;
    if (MODE == 0 && nb >= 24) { Bbase = B2; nloc = n0 - 3072; }

    f32x4 acc[4][4];
    #pragma unroll
    for (int i = 0; i < 4; i++)
        #pragma unroll
        for (int j = 0; j < 4; j++) acc[i][j] = (f32x4){0.f, 0.f, 0.f, 0.f};

    const int wbase = (tid & ~63) * 8;  // wave-uniform LDS element base
    for (int kt = kt0; kt < ktn; kt++) {
        const int k0 = kt << 6;
        __syncthreads();
        #pragma unroll
        for (int i = 0; i < 4; i++) {
            const int e = (i * 256 + tid) * 8;
            GLD16(A + (long)(m0 + (e >> 6)) * lda + k0 + (e & 63), &As[i * 2048 + wbase]);
        }
        if (MODE == 1) {
            // K-concatenated B: k<1024 -> Wo (ldb 1024); else fc_out (ldb 4096)
            const unsigned short* Bp = (k0 < 1024) ? B1 : B2;
            const int ldb = (k0 < 1024) ? 1024 : 4096;
            const int kk = (k0 < 1024) ? k0 : k0 - 1024;
            #pragma unroll
            for (int i = 0; i < 4; i++) {
                const int e = (i * 256 + tid) * 8;
                GLD16(Bp + (long)(n0 + (e >> 6)) * ldb + kk + (e & 63), &Bs[i * 2048 + wbase]);
            }
        } else {
            #pragma unroll
            for (int i = 0; i < 4; i++) {
                const int e = (i * 256 + tid) * 8;
                GLD16(Bbase + (long)(nloc + (e >> 6)) * 1024 + k0 + (e & 63), &Bs[i * 2048 + wbase]);
            }
        }
        asm volatile("s_waitcnt vmcnt(0)" ::: "memory");
        __syncthreads();
        #pragma unroll
        for (int ks = 0; ks < 2; ks++) {
            bf16x8 af[4], bfr[4];
            #pragma unroll
            for (int mf = 0; mf < 4; mf++)
                af[mf] = *reinterpret_cast<const bf16x8*>(&As[(wr * 64 + mf * 16 + l15) * 64 + ks * 32 + lhi * 8]);
            #pragma unroll
            for (int nf = 0; nf < 4; nf++)
                bfr[nf] = *reinterpret_cast<const bf16x8*>(&Bs[(wc * 64 + nf * 16 + l15) * 64 + ks * 32 + lhi * 8]);
            #pragma unroll
            for (int mf = 0; mf < 4; mf++)
                #pragma unroll
                for (int nf = 0; nf < 4; nf++)
                    acc[mf][nf] = __builtin_amdgcn_mfma_f32_16x16x32_bf16(af[mf], bfr[nf], acc[mf][nf], 0, 0, 0);
        }
    }
    // epilogue: D layout col = lane&15, row = (lane>>4)*4 + j
    #pragma unroll
    for (int nf = 0; nf < 4; nf++) {
        const int col = n0 + wc * 64 + nf * 16 + l15;
        #pragma unroll
        for (int mf = 0; mf < 4; mf++) {
            #pragma unroll
            for (int j = 0; j < 4; j++) {
                float v = acc[mf][nf][j];
                const int row = m0 + wr * 64 + mf * 16 + lhi * 4 + j;
                if (MODE == 0) {
                    if (nb < 24) {
                        ((unsigned short*)C1)[(long)row * 3072 + col] = f2bf(v);
                    } else {
                        v = gelu_tanh(v + bias[col - 3072]);
                        ((unsigned short*)C2)[(long)row * LDBUF + (col - 3072)] = f2bf(v);
                    }
                } else if (MODE == 1) {
                    if (kz == 0) v += bias[col];
                    ((float*)C1)[(long)kz * SQ * DIM + (long)row * DIM + col] = v;
                } else {
                    ((float*)C1)[(long)row * NV + col] = v + bias[col];
                }
            }
        }
    }
}

// ---------------- RoPE + QKV scatter (internal bf16) ----------------
__global__ void rope_kernel(const unsigned short* __restrict__ qkv, const float2* __restrict__ sc,
                            unsigned short* __restrict__ qt, unsigned short* __restrict__ kt,
                            unsigned short* __restrict__ vt) {
    const int t = blockIdx.x * 256 + threadIdx.x;
    const int i = t & 31;
    const int h = (t >> 5) & 15;
    const int s = t >> 9;
    const int g = h >> 2, hh = h & 3;
    const long base = (long)s * (3 * DIM) + g * 768 + hh * 64;
    const int d0 = i * 2;
    float q0, q1, v0, v1, k0, k1;
    {
        union { unsigned int u; struct { unsigned short lo, hi; }; } a, b, c;
        a.u = *(const unsigned int*)(qkv + base + d0);
        b.u = *(const unsigned int*)(qkv + base + 256 + d0);
        c.u = *(const unsigned int*)(qkv + base + 512 + d0);
        union { unsigned int i; float f; } t0;
        t0.i = (unsigned int)a.lo << 16; q0 = t0.f; t0.i = (unsigned int)a.hi << 16; q1 = t0.f;
        t0.i = (unsigned int)b.lo << 16; v0 = t0.f; t0.i = (unsigned int)b.hi << 16; v1 = t0.f;
        t0.i = (unsigned int)c.lo << 16; k0 = t0.f; t0.i = (unsigned int)c.hi << 16; k1 = t0.f;
    }
    if (d0 < 32) {
        float2 scv = sc[s * 16 + i];
        const float sn = scv.x, cs = scv.y;
        float tq0 = q0 * cs - q1 * sn, tq1 = q1 * cs + q0 * sn;
        float tk0 = k0 * cs - k1 * sn, tk1 = k1 * cs + k0 * sn;
        q0 = tq0; q1 = tq1; k0 = tk0; k1 = tk1;
    }
    const long ob = ((long)h * SQ + s) * HDIM + d0;
    qt[ob] = f2bf(q0); qt[ob + 1] = f2bf(q1);
    kt[ob] = f2bf(k0); kt[ob + 1] = f2bf(k1);
    vt[(long)h * (HDIM * SQ) + (long)d0 * SQ + s] = f2bf(v0);
    vt[(long)h * (HDIM * SQ) + (long)(d0 + 1) * SQ + s] = f2bf(v1);
}

// ---------------- causal flash attention, KVBLK=64 ----------------
__global__ __launch_bounds__(256) void attn_kernel(const unsigned short* __restrict__ qt,
                                                   const unsigned short* __restrict__ kt,
                                                   const unsigned short* __restrict__ vt,
                                                   unsigned short* __restrict__ y) {
    __shared__ unsigned short Ks[64 * 64];
    __shared__ unsigned short Vs[64 * 64];
    __shared__ unsigned short Ps[4][16 * 64];
    const int h = blockIdx.y;
    const int qb = (int)gridDim.x - 1 - (int)blockIdx.x;  // big blocks dispatch first
    const int tid = threadIdx.x, lane = tid & 63, wid = tid >> 6;
    const int l15 = lane & 15, lhi = lane >> 4;
    const int q0 = qb * 64 + wid * 16;

    bf16x8 aq[2];
    {
        const unsigned short* qp = qt + ((long)(h * SQ + q0 + l15)) * HDIM;
        aq[0] = *reinterpret_cast<const bf16x8*>(qp + lhi * 8);
        aq[1] = *reinterpret_cast<const bf16x8*>(qp + 32 + lhi * 8);
    }
    f32x4 o[4];
    #pragma unroll
    for (int nf = 0; nf < 4; nf++) o[nf] = (f32x4){0.f, 0.f, 0.f, 0.f};
    float mrow[4] = {-1e30f, -1e30f, -1e30f, -1e30f};
    float lrow[4] = {0.f, 0.f, 0.f, 0.f};

    const int wb8 = (tid & ~63) * 8;
    for (int kvt = 0; kvt <= qb; kvt++) {
        const int kv0 = kvt * 64;
        __syncthreads();
        #pragma unroll
        for (int i = 0; i < 2; i++) {
            const int e = (i * 256 + tid) * 8;
            GLD16(kt + ((long)(h * SQ + kv0 + (e >> 6))) * HDIM + (e & 63), &Ks[i * 2048 + wb8]);
            GLD16(vt + (long)h * (HDIM * SQ) + (long)(e >> 6) * SQ + kv0 + (e & 63), &Vs[i * 2048 + wb8]);
        }
        asm volatile("s_waitcnt vmcnt(0)" ::: "memory");
        __syncthreads();

        f32x4 sa[4];
        #pragma unroll
        for (int hc = 0; hc < 4; hc++) sa[hc] = (f32x4){0.f, 0.f, 0.f, 0.f};
        #pragma unroll
        for (int hc = 0; hc < 4; hc++)
            #pragma unroll
            for (int ks = 0; ks < 2; ks++) {
                bf16x8 bk = *reinterpret_cast<const bf16x8*>(&Ks[(hc * 16 + l15) * 64 + ks * 32 + lhi * 8]);
                sa[hc] = __builtin_amdgcn_mfma_f32_16x16x32_bf16(aq[ks], bk, sa[hc], 0, 0, 0);
            }
        float pr[4][4], mb[4];
        #pragma unroll
        for (int j = 0; j < 4; j++) {
            const int qi = q0 + lhi * 4 + j;
            #pragma unroll
            for (int hc = 0; hc < 4; hc++) {
                const int ki = kv0 + hc * 16 + l15;
                const float sv = sa[hc][j] * 0.125f;
                pr[hc][j] = (ki <= qi) ? sv : -1e30f;
            }
            mb[j] = fmaxf(fmaxf(pr[0][j], pr[1][j]), fmaxf(pr[2][j], pr[3][j]));
        }
        #pragma unroll
        for (int off = 1; off < 16; off <<= 1)
            #pragma unroll
            for (int j = 0; j < 4; j++) mb[j] = fmaxf(mb[j], __shfl_xor(mb[j], off));
        float alpha[4], psum[4];
        #pragma unroll
        for (int j = 0; j < 4; j++) {
            const float mn = fmaxf(mrow[j], mb[j]);
            alpha[j] = __expf(mrow[j] - mn);
            mrow[j] = mn;
            psum[j] = 0.f;
            #pragma unroll
            for (int hc = 0; hc < 4; hc++) { pr[hc][j] = __expf(pr[hc][j] - mn); psum[j] += pr[hc][j]; }
        }
        #pragma unroll
        for (int off = 1; off < 16; off <<= 1)
            #pragma unroll
            for (int j = 0; j < 4; j++) psum[j] += __shfl_xor(psum[j], off);
        #pragma unroll
        for (int j = 0; j < 4; j++) lrow[j] = lrow[j] * alpha[j] + psum[j];
        #pragma unroll
        for (int nf = 0; nf < 4; nf++)
            #pragma unroll
            for (int j = 0; j < 4; j++) o[nf][j] *= alpha[j];
        #pragma unroll
        for (int hc = 0; hc < 4; hc++)
            #pragma unroll
            for (int j = 0; j < 4; j++)
                Ps[wid][(lhi * 4 + j) * 64 + hc * 16 + l15] = f2bf(pr[hc][j]);
        bf16x8 ap[2];
        ap[0] = *reinterpret_cast<const bf16x8*>(&Ps[wid][l15 * 64 + lhi * 8]);
        ap[1] = *reinterpret_cast<const bf16x8*>(&Ps[wid][l15 * 64 + 32 + lhi * 8]);
        #pragma unroll
        for (int nf = 0; nf < 4; nf++)
            #pragma unroll
            for (int ks2 = 0; ks2 < 2; ks2++) {
                bf16x8 bv = *reinterpret_cast<const bf16x8*>(&Vs[(nf * 16 + l15) * 64 + ks2 * 32 + lhi * 8]);
                o[nf] = __builtin_amdgcn_mfma_f32_16x16x32_bf16(ap[ks2], bv, o[nf], 0, 0, 0);
            }
    }
    #pragma unroll
    for (int nf = 0; nf < 4; nf++)
        #pragma unroll
        for (int j = 0; j < 4; j++) {
            const int row = q0 + lhi * 4 + j;
            y[(long)row * LDBUF + h * HDIM + nf * 16 + l15] = f2bf(o[nf][j] / lrow[j]);
        }
}

extern "C" void kernel_launch(void* const* d_in, const int* in_sizes, int n_in,
                              void* d_out, int out_size, void* d_ws, size_t ws_size,
                              hipStream_t stream) {
    const int* idx    = (const int*)d_in[0];
    const int* pos    = (const int*)d_in[1];
    const float* emb  = (const float*)d_in[2];
    const float* Wqkv = (const float*)d_in[3];
    const float* Wo   = (const float*)d_in[4];
    const float* ln1w = (const float*)d_in[5];
    const float* ln1b = (const float*)d_in[6];
    const float* fciw = (const float*)d_in[7];
    const float* fcib = (const float*)d_in[8];
    const float* fcow = (const float*)d_in[9];
    const float* fcob = (const float*)d_in[10];
    const float* lnfw = (const float*)d_in[11];
    const float* lnfb = (const float*)d_in[12];
    const float* lmw  = (const float*)d_in[13];
    const float* lmb  = (const float*)d_in[14];

    char* ws = (char*)d_ws;
    // rotating bf16 weight buffer: per-layer 25.2 MB, LM head 105 MB
    unsigned short* wbuf = (unsigned short*)ws;   ws += (long)NV * DIM * 2;      // 105 MB
    unsigned short* wqkvb = wbuf;                                                 // 3072x1024
    unsigned short* wob   = wbuf + (long)3072 * 1024;                             // 1024x1024
    unsigned short* fcinb = wob + (long)1024 * 1024;                              // 4096x1024
    unsigned short* fcoutb= fcinb + (long)4096 * 1024;                            // 1024x4096
    float* x           = (float*)ws;          ws += (long)SQ * DIM * 4;          // 4 MB
    float* parts       = (float*)ws;          ws += (long)4 * SQ * DIM * 4;      // 16 MB
    unsigned short* h  = (unsigned short*)ws; ws += (long)SQ * DIM * 2;          // 2 MB
    unsigned short* qkv= (unsigned short*)ws; ws += (long)SQ * 3 * DIM * 2;      // 6 MB
    unsigned short* qt = (unsigned short*)ws; ws += (long)NH * SQ * HDIM * 2;    // 2 MB
    unsigned short* kt = (unsigned short*)ws; ws += (long)NH * SQ * HDIM * 2;    // 2 MB
    unsigned short* vt = (unsigned short*)ws; ws += (long)NH * SQ * HDIM * 2;    // 2 MB
    unsigned short* buf= (unsigned short*)ws; ws += (long)SQ * LDBUF * 2;        // 10 MB
    float2* sc         = (float2*)ws;         ws += (long)SQ * 16 * 8;           // 128 KB

    sincos_kernel<<<64, 256, 0, stream>>>(pos, sc);
    embed_kernel<<<SQ, 256, 0, stream>>>(idx, emb, x);

    for (int l = 0; l < NL; l++) {
        // convert this layer's weights to bf16 (stream-ordered before use)
        cvt_kernel<<<1536, 256, 0, stream>>>(Wqkv + (long)l * 3 * DIM * DIM, wqkvb);
        cvt_kernel<<< 512, 256, 0, stream>>>(Wo   + (long)l * DIM * DIM,     wob);
        cvt_kernel<<<2048, 256, 0, stream>>>(fciw + (long)l * FFD * DIM,     fcinb);
        cvt_kernel<<<2048, 256, 0, stream>>>(fcow + (long)l * DIM * FFD,     fcoutb);

        if (l == 0) ln_kernel<false><<<SQ, 256, 0, stream>>>(x, nullptr, ln1w, ln1b, h);
        else ln_kernel<true><<<SQ, 256, 0, stream>>>(x, parts, ln1w + (long)l * DIM, ln1b + (long)l * DIM, h);

        // merged QKV + fc_in: N = 3072 + 4096, grid 448
        gemm_bb<0><<<448, 256, 0, stream>>>(h, DIM, wqkvb, fcinb, fcib + (long)l * FFD,
                                            qkv, buf + DIM);
        rope_kernel<<<2048, 256, 0, stream>>>(qkv, sc, qt, kt, vt);
        attn_kernel<<<dim3(16, NH), 256, 0, stream>>>(qt, kt, vt, buf);
        // merged Wo + fc_out over K=5120, split-K=4 -> parts
        gemm_bb<1><<<256, 256, 0, stream>>>(buf, LDBUF, wob, fcoutb, fcob + (long)l * DIM,
                                            parts, nullptr);
    }
    cvt_kernel<<<25600, 256, 0, stream>>>(lmw, wbuf);  // LM head weights -> bf16
    ln_kernel<true><<<SQ, 256, 0, stream>>>(x, parts, lnfw, lnfb, h);
    gemm_bb<2><<<3200, 256, 0, stream>>>(h, DIM, wbuf, nullptr, lmb, d_out, nullptr);
}

// Round 5
// 1348.433 us; speedup vs baseline: 2.0737x; 1.1110x over previous
//
#include <hip/hip_runtime.h>

#define SQ 1024
#define DIM 1024
#define NH 16
#define HDIM 64
#define FFD 4096
#define NV 51200
#define NL 8
#define LDBUF 5120  // [yb(1024) | ff(4096)] row stride

typedef __bf16 bf16x8 __attribute__((ext_vector_type(8)));
typedef float f32x4 __attribute__((ext_vector_type(4)));

__device__ __forceinline__ unsigned short f2bf(float f) {
    union { float f; unsigned int i; } v; v.f = f;
    unsigned int r = v.i + 0x7fffu + ((v.i >> 16) & 1u);
    return (unsigned short)(r >> 16);
}
__device__ __forceinline__ float gelu_tanh(float x) {
    float x3 = x * x * x;
    return 0.5f * x * (1.0f + tanhf(0.79788456080286535588f * (x + 0.044715f * x3)));
}

#define GLD16(gp, lp) __builtin_amdgcn_global_load_lds( \
    (__attribute__((address_space(1))) void*)(gp), \
    (__attribute__((address_space(3))) void*)(lp), 16, 0, 0)
#define VMCNT0 asm volatile("s_waitcnt vmcnt(0)" ::: "memory")

// ---------------- fused per-layer fp32 -> bf16 weight conversion ----------------
// ranges: Wqkv 3M (1536 blk) | Wo 1M (512) | fc_in 4M (2048) | fc_out 4M (2048)
__global__ void cvt4_kernel(const float* __restrict__ w0, const float* __restrict__ w1,
                            const float* __restrict__ w2, const float* __restrict__ w3,
                            unsigned short* __restrict__ d0, unsigned short* __restrict__ d1,
                            unsigned short* __restrict__ d2, unsigned short* __restrict__ d3) {
    const int b = blockIdx.x;
    const float* s; unsigned short* d; long off;
    if (b < 1536)      { s = w0; d = d0; off = (long)b * 2048; }
    else if (b < 2048) { s = w1; d = d1; off = (long)(b - 1536) * 2048; }
    else if (b < 4096) { s = w2; d = d2; off = (long)(b - 2048) * 2048; }
    else               { s = w3; d = d3; off = (long)(b - 4096) * 2048; }
    const long i = off + threadIdx.x * 8;
    float4 a = *reinterpret_cast<const float4*>(s + i);
    float4 c = *reinterpret_cast<const float4*>(s + i + 4);
    bf16x8 w;
    w[0] = (__bf16)a.x; w[1] = (__bf16)a.y; w[2] = (__bf16)a.z; w[3] = (__bf16)a.w;
    w[4] = (__bf16)c.x; w[5] = (__bf16)c.y; w[6] = (__bf16)c.z; w[7] = (__bf16)c.w;
    *reinterpret_cast<bf16x8*>(d + i) = w;
}
__global__ void cvt_kernel(const float* __restrict__ src, unsigned short* __restrict__ dst) {
    const long i = ((long)blockIdx.x * 256 + threadIdx.x) * 8;
    float4 a = *reinterpret_cast<const float4*>(src + i);
    float4 b = *reinterpret_cast<const float4*>(src + i + 4);
    bf16x8 w;
    w[0] = (__bf16)a.x; w[1] = (__bf16)a.y; w[2] = (__bf16)a.z; w[3] = (__bf16)a.w;
    w[4] = (__bf16)b.x; w[5] = (__bf16)b.y; w[6] = (__bf16)b.z; w[7] = (__bf16)b.w;
    *reinterpret_cast<bf16x8*>(dst + i) = w;
}

// ---------------- sin/cos table ----------------
__global__ void sincos_kernel(const int* __restrict__ pos, float2* __restrict__ sc) {
    const int t = blockIdx.x * 256 + threadIdx.x;
    if (t >= SQ * 16) return;
    const int s = t >> 4, i = t & 15;
    const float ang = (float)pos[s] * powf(10000.0f, -(float)i / 16.0f);
    sc[t] = make_float2(sinf(ang), cosf(ang));
}

// ---------------- embedding gather ----------------
__global__ void embed_kernel(const int* __restrict__ idx, const float* __restrict__ emb,
                             float* __restrict__ x) {
    const int s = blockIdx.x;
    const int d = threadIdx.x * 4;
    const int row = idx[s];
    *reinterpret_cast<float4*>(x + (long)s * DIM + d) =
        *reinterpret_cast<const float4*>(emb + (long)row * DIM + d);
}

// ---------------- fused (residual reduce) + layernorm ----------------
template <bool RED>
__global__ __launch_bounds__(256) void ln_kernel(float* __restrict__ x,
                                                 const float* __restrict__ part,
                                                 const float* __restrict__ w,
                                                 const float* __restrict__ b,
                                                 unsigned short* __restrict__ out) {
    __shared__ float red[8];
    const int s = blockIdx.x, tid = threadIdx.x;
    const long fidx = (long)s * 256 + tid;
    float4 v = reinterpret_cast<const float4*>(x)[fidx];
    if (RED) {
        #pragma unroll
        for (int z = 0; z < 4; z++) {
            float4 p = reinterpret_cast<const float4*>(part + (long)z * SQ * DIM)[fidx];
            v.x += p.x; v.y += p.y; v.z += p.z; v.w += p.w;
        }
        reinterpret_cast<float4*>(x)[fidx] = v;
    }
    float sum = v.x + v.y + v.z + v.w;
    float sq = v.x * v.x + v.y * v.y + v.z * v.z + v.w * v.w;
    #pragma unroll
    for (int off = 32; off; off >>= 1) { sum += __shfl_xor(sum, off); sq += __shfl_xor(sq, off); }
    const int wid = tid >> 6, lane = tid & 63;
    if (lane == 0) { red[wid * 2] = sum; red[wid * 2 + 1] = sq; }
    __syncthreads();
    sum = red[0] + red[2] + red[4] + red[6];
    sq  = red[1] + red[3] + red[5] + red[7];
    const float mu = sum * (1.0f / DIM);
    const float var = sq * (1.0f / DIM) - mu * mu;
    const float rstd = rsqrtf(var + 1e-5f);
    const int d = tid * 4;
    float vv[4] = {v.x, v.y, v.z, v.w};
    ushort4 o;
    unsigned short* op = (unsigned short*)&o;
    #pragma unroll
    for (int j = 0; j < 4; j++)
        op[j] = f2bf((vv[j] - mu) * rstd * w[d + j] + b[d + j]);
    *reinterpret_cast<ushort4*>(out + (long)s * DIM + d) = o;
}

// ---------------- 128x128 2-phase GEMM (layer GEMMs) ----------------
// T3 2-phase: stage(t+1) issued before compute(t); one vmcnt(0)+barrier per K-step.
// T2 swizzle: LDS 16B-slot c8 ^= row&7, applied on gload source AND ds_read.
// MODE 0: QKV+FCIN merged over N (grid 448). nb<24: C1=qkv(ldc 3072); else gelu -> C2 (ldc LDBUF).
// MODE 1: Wo+FCOUT merged over K=5120, split-K=4 (grid 256) -> fp32 parts, bias kz==0.
template <int MODE>
__global__ __launch_bounds__(256) void gemm128(const unsigned short* __restrict__ A, int lda,
                                               const unsigned short* __restrict__ B1,
                                               const unsigned short* __restrict__ B2,
                                               const float* __restrict__ bias,
                                               void* __restrict__ C1, void* __restrict__ C2) {
    __shared__ __align__(16) unsigned short As[2][128 * 64];
    __shared__ __align__(16) unsigned short Bs[2][128 * 64];
    const int tid = threadIdx.x;
    const int nwg = gridDim.x, qch = nwg >> 3;
    const int sb = (blockIdx.x & 7) * qch + (blockIdx.x >> 3);  // XCD-chunked (nwg%8==0)
    int mb, nb, kz, kt0, ktn;
    if (MODE == 1) { kz = sb & 3; nb = (sb >> 2) & 7; mb = sb >> 5; kt0 = kz * 20; ktn = kt0 + 20; }
    else           { kz = 0; mb = sb & 7; nb = sb >> 3; kt0 = 0; ktn = 16; }
    const int m0 = mb * 128, n0 = nb * 128;
    const int lane = tid & 63, wid = tid >> 6;
    const int l15 = lane & 15, lhi = lane >> 4;
    const int wr = wid >> 1, wc = wid & 1;
    const int sw = l15 & 7;  // read-side swizzle xor

    const unsigned short* Bbase = B1;
    int nloc = n0;
    if (MODE == 0 && nb >= 24) { Bbase = B2; nloc = n0 - 3072; }

    f32x4 acc[4][4];
    #pragma unroll
    for (int i = 0; i < 4; i++)
        #pragma unroll
        for (int j = 0; j < 4; j++) acc[i][j] = (f32x4){0.f, 0.f, 0.f, 0.f};

    const int wbase = (tid & ~63) * 8;

    auto stage = [&](int buf, int kt) {
        const int k0 = kt << 6;
        #pragma unroll
        for (int i = 0; i < 4; i++) {
            const int e = (i * 256 + tid) * 8;
            const int r = e >> 6;
            const int cs = (((e >> 3) & 7) ^ (r & 7)) * 8;  // pre-swizzled source
            GLD16(A + (long)(m0 + r) * lda + k0 + cs, &As[buf][i * 2048 + wbase]);
        }
        if (MODE == 1) {
            const unsigned short* Bp = (k0 < 1024) ? B1 : B2;
            const int ldb = (k0 < 1024) ? 1024 : 4096;
            const int kk = (k0 < 1024) ? k0 : k0 - 1024;
            #pragma unroll
            for (int i = 0; i < 4; i++) {
                const int e = (i * 256 + tid) * 8;
                const int r = e >> 6;
                const int cs = (((e >> 3) & 7) ^ (r & 7)) * 8;
                GLD16(Bp + (long)(n0 + r) * ldb + kk + cs, &Bs[buf][i * 2048 + wbase]);
            }
        } else {
            #pragma unroll
            for (int i = 0; i < 4; i++) {
                const int e = (i * 256 + tid) * 8;
                const int r = e >> 6;
                const int cs = (((e >> 3) & 7) ^ (r & 7)) * 8;
                GLD16(Bbase + (long)(nloc + r) * 1024 + k0 + cs, &Bs[buf][i * 2048 + wbase]);
            }
        }
    };
    auto compute = [&](int buf) {
        #pragma unroll
        for (int ks = 0; ks < 2; ks++) {
            bf16x8 af[4], bfr[4];
            #pragma unroll
            for (int mf = 0; mf < 4; mf++)
                af[mf] = *reinterpret_cast<const bf16x8*>(
                    &As[buf][(wr * 64 + mf * 16 + l15) * 64 + ((ks * 4 + lhi) ^ sw) * 8]);
            #pragma unroll
            for (int nf = 0; nf < 4; nf++)
                bfr[nf] = *reinterpret_cast<const bf16x8*>(
                    &Bs[buf][(wc * 64 + nf * 16 + l15) * 64 + ((ks * 4 + lhi) ^ sw) * 8]);
            #pragma unroll
            for (int mf = 0; mf < 4; mf++)
                #pragma unroll
                for (int nf = 0; nf < 4; nf++)
                    acc[mf][nf] = __builtin_amdgcn_mfma_f32_16x16x32_bf16(af[mf], bfr[nf], acc[mf][nf], 0, 0, 0);
        }
    };

    int cur = 0;
    stage(0, kt0);
    VMCNT0; __syncthreads();
    for (int kt = kt0; kt < ktn; kt++) {
        if (kt + 1 < ktn) stage(cur ^ 1, kt + 1);
        compute(cur);
        if (kt + 1 < ktn) { VMCNT0; __syncthreads(); cur ^= 1; }
    }

    #pragma unroll
    for (int nf = 0; nf < 4; nf++) {
        const int col = n0 + wc * 64 + nf * 16 + l15;
        #pragma unroll
        for (int mf = 0; mf < 4; mf++) {
            #pragma unroll
            for (int j = 0; j < 4; j++) {
                float v = acc[mf][nf][j];
                const int row = m0 + wr * 64 + mf * 16 + lhi * 4 + j;
                if (MODE == 0) {
                    if (nb < 24) {
                        ((unsigned short*)C1)[(long)row * 3072 + col] = f2bf(v);
                    } else {
                        v = gelu_tanh(v + bias[col - 3072]);
                        ((unsigned short*)C2)[(long)row * LDBUF + (col - 3072)] = f2bf(v);
                    }
                } else {
                    if (kz == 0) v += bias[col];
                    ((float*)C1)[(long)kz * SQ * DIM + (long)row * DIM + col] = v;
                }
            }
        }
    }
}

// ---------------- 256x256 2-phase GEMM (LM head), 8 waves, 128 KB LDS ----------------
__global__ __launch_bounds__(512) void gemm256(const unsigned short* __restrict__ A,
                                               const unsigned short* __restrict__ B,
                                               const float* __restrict__ bias,
                                               float* __restrict__ C) {
    __shared__ __align__(16) unsigned short As[2][256 * 64];
    __shared__ __align__(16) unsigned short Bs[2][256 * 64];
    const int tid = threadIdx.x;
    const int nwg = gridDim.x, qch = nwg >> 3;
    const int sb = (blockIdx.x & 7) * qch + (blockIdx.x >> 3);  // XCD-chunked (800%8==0)
    const int mb = sb & 3, nb = sb >> 2;
    const int m0 = mb * 256, n0 = nb * 256;
    const int lane = tid & 63, wid = tid >> 6;
    const int l15 = lane & 15, lhi = lane >> 4;
    const int wm = wid >> 2, wn = wid & 3;  // 2 x 4 wave grid; per-wave C = 128 x 64
    const int sw = l15 & 7;

    f32x4 acc[8][4];
    #pragma unroll
    for (int i = 0; i < 8; i++)
        #pragma unroll
        for (int j = 0; j < 4; j++) acc[i][j] = (f32x4){0.f, 0.f, 0.f, 0.f};

    const int wbase = (tid & ~63) * 8;

    auto stage = [&](int buf, int kt) {
        const int k0 = kt << 6;
        #pragma unroll
        for (int i = 0; i < 4; i++) {
            const int e = (i * 512 + tid) * 8;
            const int r = e >> 6;
            const int cs = (((e >> 3) & 7) ^ (r & 7)) * 8;
            GLD16(A + (long)(m0 + r) * 1024 + k0 + cs, &As[buf][i * 4096 + wbase]);
            GLD16(B + (long)(n0 + r) * 1024 + k0 + cs, &Bs[buf][i * 4096 + wbase]);
        }
    };
    auto compute = [&](int buf) {
        #pragma unroll
        for (int ks = 0; ks < 2; ks++) {
            bf16x8 af[8], bfr[4];
            #pragma unroll
            for (int mf = 0; mf < 8; mf++)
                af[mf] = *reinterpret_cast<const bf16x8*>(
                    &As[buf][(wm * 128 + mf * 16 + l15) * 64 + ((ks * 4 + lhi) ^ sw) * 8]);
            #pragma unroll
            for (int nf = 0; nf < 4; nf++)
                bfr[nf] = *reinterpret_cast<const bf16x8*>(
                    &Bs[buf][(wn * 64 + nf * 16 + l15) * 64 + ((ks * 4 + lhi) ^ sw) * 8]);
            #pragma unroll
            for (int mf = 0; mf < 8; mf++)
                #pragma unroll
                for (int nf = 0; nf < 4; nf++)
                    acc[mf][nf] = __builtin_amdgcn_mfma_f32_16x16x32_bf16(af[mf], bfr[nf], acc[mf][nf], 0, 0, 0);
        }
    };

    int cur = 0;
    stage(0, 0);
    VMCNT0; __syncthreads();
    for (int kt = 0; kt < 16; kt++) {
        if (kt < 15) stage(cur ^ 1, kt + 1);
        compute(cur);
        if (kt < 15) { VMCNT0; __syncthreads(); cur ^= 1; }
    }

    #pragma unroll
    for (int nf = 0; nf < 4; nf++) {
        const int col = n0 + wn * 64 + nf * 16 + l15;
        const float bv = bias[col];
        #pragma unroll
        for (int mf = 0; mf < 8; mf++) {
            #pragma unroll
            for (int j = 0; j < 4; j++) {
                const int row = m0 + wm * 128 + mf * 16 + lhi * 4 + j;
                C[(long)row * NV + col] = acc[mf][nf][j] + bv;
            }
        }
    }
}

// ---------------- RoPE + QKV scatter (internal bf16) ----------------
__global__ void rope_kernel(const unsigned short* __restrict__ qkv, const float2* __restrict__ sc,
                            unsigned short* __restrict__ qt, unsigned short* __restrict__ kt,
                            unsigned short* __restrict__ vt) {
    const int t = blockIdx.x * 256 + threadIdx.x;
    const int i = t & 31;
    const int h = (t >> 5) & 15;
    const int s = t >> 9;
    const int g = h >> 2, hh = h & 3;
    const long base = (long)s * (3 * DIM) + g * 768 + hh * 64;
    const int d0 = i * 2;
    float q0, q1, v0, v1, k0, k1;
    {
        union { unsigned int u; struct { unsigned short lo, hi; }; } a, b, c;
        a.u = *(const unsigned int*)(qkv + base + d0);
        b.u = *(const unsigned int*)(qkv + base + 256 + d0);
        c.u = *(const unsigned int*)(qkv + base + 512 + d0);
        union { unsigned int i; float f; } t0;
        t0.i = (unsigned int)a.lo << 16; q0 = t0.f; t0.i = (unsigned int)a.hi << 16; q1 = t0.f;
        t0.i = (unsigned int)b.lo << 16; v0 = t0.f; t0.i = (unsigned int)b.hi << 16; v1 = t0.f;
        t0.i = (unsigned int)c.lo << 16; k0 = t0.f; t0.i = (unsigned int)c.hi << 16; k1 = t0.f;
    }
    if (d0 < 32) {
        float2 scv = sc[s * 16 + i];
        const float sn = scv.x, cs = scv.y;
        float tq0 = q0 * cs - q1 * sn, tq1 = q1 * cs + q0 * sn;
        float tk0 = k0 * cs - k1 * sn, tk1 = k1 * cs + k0 * sn;
        q0 = tq0; q1 = tq1; k0 = tk0; k1 = tk1;
    }
    const long ob = ((long)h * SQ + s) * HDIM + d0;
    qt[ob] = f2bf(q0); qt[ob + 1] = f2bf(q1);
    kt[ob] = f2bf(k0); kt[ob + 1] = f2bf(k1);
    vt[(long)h * (HDIM * SQ) + (long)d0 * SQ + s] = f2bf(v0);
    vt[(long)h * (HDIM * SQ) + (long)(d0 + 1) * SQ + s] = f2bf(v1);
}

// ---------------- causal flash attention, KVBLK=64, 2-phase K/V dbuf, swizzled LDS ----------------
__global__ __launch_bounds__(256) void attn_kernel(const unsigned short* __restrict__ qt,
                                                   const unsigned short* __restrict__ kt,
                                                   const unsigned short* __restrict__ vt,
                                                   unsigned short* __restrict__ y) {
    __shared__ __align__(16) unsigned short Ks[2][64 * 64];
    __shared__ __align__(16) unsigned short Vs[2][64 * 64];
    __shared__ __align__(16) unsigned short Ps[4][16 * 64];
    const int h = blockIdx.y;
    const int qb = (int)gridDim.x - 1 - (int)blockIdx.x;  // big blocks dispatch first
    const int tid = threadIdx.x, lane = tid & 63, wid = tid >> 6;
    const int l15 = lane & 15, lhi = lane >> 4;
    const int q0 = qb * 64 + wid * 16;
    const int sw = l15 & 7;

    bf16x8 aq[2];
    {
        const unsigned short* qp = qt + ((long)(h * SQ + q0 + l15)) * HDIM;
        aq[0] = *reinterpret_cast<const bf16x8*>(qp + lhi * 8);
        aq[1] = *reinterpret_cast<const bf16x8*>(qp + 32 + lhi * 8);
    }
    f32x4 o[4];
    #pragma unroll
    for (int nf = 0; nf < 4; nf++) o[nf] = (f32x4){0.f, 0.f, 0.f, 0.f};
    float mrow[4] = {-1e30f, -1e30f, -1e30f, -1e30f};
    float lrow[4] = {0.f, 0.f, 0.f, 0.f};

    const int wb8 = (tid & ~63) * 8;
    auto stageKV = [&](int buf, int kv0) {
        #pragma unroll
        for (int i = 0; i < 2; i++) {
            const int e = (i * 256 + tid) * 8;
            const int r = e >> 6;
            const int cs = (((e >> 3) & 7) ^ (r & 7)) * 8;
            GLD16(kt + ((long)(h * SQ + kv0 + r)) * HDIM + cs, &Ks[buf][i * 2048 + wb8]);
            GLD16(vt + (long)h * (HDIM * SQ) + (long)r * SQ + kv0 + cs, &Vs[buf][i * 2048 + wb8]);
        }
    };

    int cur = 0;
    stageKV(0, 0);
    VMCNT0; __syncthreads();
    for (int kvt = 0; kvt <= qb; kvt++) {
        const int kv0 = kvt * 64;
        if (kvt < qb) stageKV(cur ^ 1, kv0 + 64);

        f32x4 sa[4];
        #pragma unroll
        for (int hc = 0; hc < 4; hc++) sa[hc] = (f32x4){0.f, 0.f, 0.f, 0.f};
        #pragma unroll
        for (int hc = 0; hc < 4; hc++)
            #pragma unroll
            for (int ks = 0; ks < 2; ks++) {
                bf16x8 bk = *reinterpret_cast<const bf16x8*>(
                    &Ks[cur][(hc * 16 + l15) * 64 + ((ks * 4 + lhi) ^ sw) * 8]);
                sa[hc] = __builtin_amdgcn_mfma_f32_16x16x32_bf16(aq[ks], bk, sa[hc], 0, 0, 0);
            }
        float pr[4][4], mb[4];
        #pragma unroll
        for (int j = 0; j < 4; j++) {
            const int qi = q0 + lhi * 4 + j;
            #pragma unroll
            for (int hc = 0; hc < 4; hc++) {
                const int ki = kv0 + hc * 16 + l15;
                const float sv = sa[hc][j] * 0.125f;
                pr[hc][j] = (ki <= qi) ? sv : -1e30f;
            }
            mb[j] = fmaxf(fmaxf(pr[0][j], pr[1][j]), fmaxf(pr[2][j], pr[3][j]));
        }
        #pragma unroll
        for (int off = 1; off < 16; off <<= 1)
            #pragma unroll
            for (int j = 0; j < 4; j++) mb[j] = fmaxf(mb[j], __shfl_xor(mb[j], off));
        float alpha[4], psum[4];
        #pragma unroll
        for (int j = 0; j < 4; j++) {
            const float mn = fmaxf(mrow[j], mb[j]);
            alpha[j] = __expf(mrow[j] - mn);
            mrow[j] = mn;
            psum[j] = 0.f;
            #pragma unroll
            for (int hc = 0; hc < 4; hc++) { pr[hc][j] = __expf(pr[hc][j] - mn); psum[j] += pr[hc][j]; }
        }
        #pragma unroll
        for (int off = 1; off < 16; off <<= 1)
            #pragma unroll
            for (int j = 0; j < 4; j++) psum[j] += __shfl_xor(psum[j], off);
        #pragma unroll
        for (int j = 0; j < 4; j++) lrow[j] = lrow[j] * alpha[j] + psum[j];
        #pragma unroll
        for (int nf = 0; nf < 4; nf++)
            #pragma unroll
            for (int j = 0; j < 4; j++) o[nf][j] *= alpha[j];
        // P (D-layout) -> wave-private LDS (swizzled) -> A-layout
        #pragma unroll
        for (int hc = 0; hc < 4; hc++)
            #pragma unroll
            for (int j = 0; j < 4; j++) {
                const int prow = lhi * 4 + j;
                const int pc8 = (hc * 2 + (l15 >> 3)) ^ (prow & 7);
                Ps[wid][prow * 64 + pc8 * 8 + (l15 & 7)] = f2bf(pr[hc][j]);
            }
        bf16x8 ap[2];
        ap[0] = *reinterpret_cast<const bf16x8*>(&Ps[wid][l15 * 64 + ((0 + lhi) ^ sw) * 8]);
        ap[1] = *reinterpret_cast<const bf16x8*>(&Ps[wid][l15 * 64 + ((4 + lhi) ^ sw) * 8]);
        #pragma unroll
        for (int nf = 0; nf < 4; nf++)
            #pragma unroll
            for (int ks2 = 0; ks2 < 2; ks2++) {
                bf16x8 bv = *reinterpret_cast<const bf16x8*>(
                    &Vs[cur][(nf * 16 + l15) * 64 + ((ks2 * 4 + lhi) ^ sw) * 8]);
                o[nf] = __builtin_amdgcn_mfma_f32_16x16x32_bf16(ap[ks2], bv, o[nf], 0, 0, 0);
            }
        if (kvt < qb) { VMCNT0; __syncthreads(); cur ^= 1; }
    }
    #pragma unroll
    for (int nf = 0; nf < 4; nf++)
        #pragma unroll
        for (int j = 0; j < 4; j++) {
            const int row = q0 + lhi * 4 + j;
            y[(long)row * LDBUF + h * HDIM + nf * 16 + l15] = f2bf(o[nf][j] / lrow[j]);
        }
}

extern "C" void kernel_launch(void* const* d_in, const int* in_sizes, int n_in,
                              void* d_out, int out_size, void* d_ws, size_t ws_size,
                              hipStream_t stream) {
    const int* idx    = (const int*)d_in[0];
    const int* pos    = (const int*)d_in[1];
    const float* emb  = (const float*)d_in[2];
    const float* Wqkv = (const float*)d_in[3];
    const float* Wo   = (const float*)d_in[4];
    const float* ln1w = (const float*)d_in[5];
    const float* ln1b = (const float*)d_in[6];
    const float* fciw = (const float*)d_in[7];
    const float* fcib = (const float*)d_in[8];
    const float* fcow = (const float*)d_in[9];
    const float* fcob = (const float*)d_in[10];
    const float* lnfw = (const float*)d_in[11];
    const float* lnfb = (const float*)d_in[12];
    const float* lmw  = (const float*)d_in[13];
    const float* lmb  = (const float*)d_in[14];

    char* ws = (char*)d_ws;
    unsigned short* wbuf = (unsigned short*)ws;   ws += (long)NV * DIM * 2;      // 105 MB
    unsigned short* wqkvb = wbuf;                                                 // 3072x1024
    unsigned short* wob   = wbuf + (long)3072 * 1024;                             // 1024x1024
    unsigned short* fcinb = wob + (long)1024 * 1024;                              // 4096x1024
    unsigned short* fcoutb= fcinb + (long)4096 * 1024;                            // 1024x4096
    float* x           = (float*)ws;          ws += (long)SQ * DIM * 4;          // 4 MB
    float* parts       = (float*)ws;          ws += (long)4 * SQ * DIM * 4;      // 16 MB
    unsigned short* h  = (unsigned short*)ws; ws += (long)SQ * DIM * 2;          // 2 MB
    unsigned short* qkv= (unsigned short*)ws; ws += (long)SQ * 3 * DIM * 2;      // 6 MB
    unsigned short* qt = (unsigned short*)ws; ws += (long)NH * SQ * HDIM * 2;    // 2 MB
    unsigned short* kt = (unsigned short*)ws; ws += (long)NH * SQ * HDIM * 2;    // 2 MB
    unsigned short* vt = (unsigned short*)ws; ws += (long)NH * SQ * HDIM * 2;    // 2 MB
    unsigned short* buf= (unsigned short*)ws; ws += (long)SQ * LDBUF * 2;        // 10 MB
    float2* sc         = (float2*)ws;         ws += (long)SQ * 16 * 8;           // 128 KB

    sincos_kernel<<<64, 256, 0, stream>>>(pos, sc);
    embed_kernel<<<SQ, 256, 0, stream>>>(idx, emb, x);

    for (int l = 0; l < NL; l++) {
        cvt4_kernel<<<6144, 256, 0, stream>>>(Wqkv + (long)l * 3 * DIM * DIM,
                                              Wo   + (long)l * DIM * DIM,
                                              fciw + (long)l * FFD * DIM,
                                              fcow + (long)l * DIM * FFD,
                                              wqkvb, wob, fcinb, fcoutb);

        if (l == 0) ln_kernel<false><<<SQ, 256, 0, stream>>>(x, nullptr, ln1w, ln1b, h);
        else ln_kernel<true><<<SQ, 256, 0, stream>>>(x, parts, ln1w + (long)l * DIM, ln1b + (long)l * DIM, h);

        gemm128<0><<<448, 256, 0, stream>>>(h, DIM, wqkvb, fcinb, fcib + (long)l * FFD,
                                            qkv, buf + DIM);
        rope_kernel<<<2048, 256, 0, stream>>>(qkv, sc, qt, kt, vt);
        attn_kernel<<<dim3(16, NH), 256, 0, stream>>>(qt, kt, vt, buf);
        gemm128<1><<<256, 256, 0, stream>>>(buf, LDBUF, wob, fcoutb, fcob + (long)l * DIM,
                                            parts, nullptr);
    }
    cvt_kernel<<<25600, 256, 0, stream>>>(lmw, wbuf);
    ln_kernel<true><<<SQ, 256, 0, stream>>>(x, parts, lnfw, lnfb, h);
    gemm256<<<800, 512, 0, stream>>>(h, wbuf, lmb, (float*)d_out);
}